// Round 1
// 159.228 us; speedup vs baseline: 1.1127x; 1.1127x over previous
//
#include <hip/hip_runtime.h>
#include <math.h>

#define HEADS 8
#define DIM   64
#define DK    24
#define DHK   3
#define BB    4
#define HH    128
#define WW    128
#define NN    (HH*WW)
#define QSCALE 0.125f

// ---------------------------------------------------------------------------
// K1 v2: Sp[b,i,c] += block-partial of sum_n imap[n,i]*x[n,c]
// grid 1024 (4b x 256 chunks of 64 tokens), 256 threads.
// vs v1: 4x more blocks (16 waves/CU vs 4), 16-iter token loop (vs 64),
// LDS tree reduce then atomicAdd into Sp[4,1536] (pre-zeroed) -- kills the
// 1.57MB Sp_part write + K2's 393KB/block re-read.
// ---------------------------------------------------------------------------
__global__ __launch_bounds__(256) void s_reduce(
    const float* __restrict__ imap,   // [B*N,24]
    const float* __restrict__ x,      // [B*N,64]
    float* __restrict__ Sp)           // [4,1536] pre-zeroed
{
    __shared__ float part[4*1536];
    const int tid = threadIdx.x;
    const int blk = blockIdx.x;
    const int b = blk >> 8, chunk = blk & 255;
    const int w = tid >> 6, lane = tid & 63;
    const int cq = lane & 15;         // c = cq*4
    const int ig = lane >> 4;         // i = ig*6 .. +5

    const long tok0 = (long)b * NN + chunk * 64 + w * 16;
    const float* xp = x    + tok0 * 64 + cq * 4;
    const float* mp = imap + tok0 * 24 + ig * 6;

    float acc[6][4];
    #pragma unroll
    for (int r = 0; r < 6; ++r)
        #pragma unroll
        for (int q = 0; q < 4; ++q) acc[r][q] = 0.f;

    #pragma unroll 4
    for (int t = 0; t < 16; ++t) {
        float4 xv = *(const float4*)(xp + t * 64);
        float2 m0 = *(const float2*)(mp + t * 24);
        float2 m1 = *(const float2*)(mp + t * 24 + 2);
        float2 m2 = *(const float2*)(mp + t * 24 + 4);
        float mm[6] = {m0.x, m0.y, m1.x, m1.y, m2.x, m2.y};
        #pragma unroll
        for (int r = 0; r < 6; ++r) {
            acc[r][0] += mm[r] * xv.x;
            acc[r][1] += mm[r] * xv.y;
            acc[r][2] += mm[r] * xv.z;
            acc[r][3] += mm[r] * xv.w;
        }
    }

    float* pp = part + w * 1536;
    #pragma unroll
    for (int r = 0; r < 6; ++r) {
        float4 v = {acc[r][0], acc[r][1], acc[r][2], acc[r][3]};
        *(float4*)(pp + (ig * 6 + r) * 64 + cq * 4) = v;
    }
    __syncthreads();

    for (int e = tid; e < 1536; e += 256)
        atomicAdd(&Sp[b * 1536 + e],
                  part[e] + part[1536 + e] + part[3072 + e] + part[4608 + e]);
}

// ---------------------------------------------------------------------------
// K2 v2: attention, one block per (batch, head). grid 32 x 192 thr.
// wave k3 (=dhk row) owns one attention row; lanes = d (or c).
// Softmax is wave-parallel shfl (was: 24 serial threads).
// Wv slice staged in LDS with stride 65 (conflict-free strided reads).
// Pt[b,o,c] accumulated across the 8 h-blocks via atomicAdd (pre-zeroed).
// ---------------------------------------------------------------------------
__global__ __launch_bounds__(192) void attn_fused(
    const float* __restrict__ Sp,      // [4,1536]
    const float* __restrict__ Wk,      // [24,24]
    const float* __restrict__ Wq,      // [64,512]
    const float* __restrict__ Wv,      // [64,512]
    const float* __restrict__ rescale, // [8]
    const float* __restrict__ Wp,      // [24,24]
    float* __restrict__ Pt)            // [4,24,64] pre-zeroed
{
    __shared__ float Sp_l[1536];
    __shared__ float sS[192];        // S rows for this block's 3 ch (later reused for M)
    __shared__ float sP[192];        // softmax'd rows
    __shared__ float Wv_l[64 * 65];  // Wv[:, h*64 .. +63], padded stride 65

    const int tid = threadIdx.x, blk = blockIdx.x;
    const int b = blk >> 3, h = blk & 7;
    const int k3 = tid >> 6, lane = tid & 63;   // wave id / lane

    for (int e = tid; e < 1536; e += 192) Sp_l[e] = Sp[b * 1536 + e];
    for (int e = tid; e < 4096; e += 192) {
        int c = e >> 6, d = e & 63;
        Wv_l[c * 65 + d] = Wv[c * 512 + h * 64 + d];
    }
    __syncthreads();

    // S row: ch = h*3+k3, element c = lane.  S[ch,c] = sum_i Wk[i,ch]*Sp[i,c]
    {
        const float* wk = Wk + (h * 3 + k3);
        float s = 0.f;
        #pragma unroll
        for (int i = 0; i < 24; ++i) s += wk[i * 24] * Sp_l[i * 64 + lane];
        sS[k3 * 64 + lane] = s;
    }
    __syncthreads();

    // att row (d = lane) + wave-parallel softmax over d
    {
        const float* wq = Wq + h * 64 + lane;
        const float* sr = sS + k3 * 64;
        float a = 0.f;
        for (int c = 0; c < 64; ++c) a += sr[c] * wq[c * 512];
        a *= QSCALE * rescale[h];
        float mx = a;
        #pragma unroll
        for (int off = 32; off >= 1; off >>= 1)
            mx = fmaxf(mx, __shfl_xor(mx, off, 64));
        float e = expf(a - mx);
        float sum = e;
        #pragma unroll
        for (int off = 32; off >= 1; off >>= 1)
            sum += __shfl_xor(sum, off, 64);
        sP[k3 * 64 + lane] = e / sum;
    }
    __syncthreads();

    // M row: c = lane.  M[ch,c] = sum_d P[ch,d]*Wv[c, h*64+d].  Reuse sS for M.
    {
        const float* pr = sP + k3 * 64;
        const float* wv = Wv_l + lane * 65;
        float m = 0.f;
        #pragma unroll
        for (int d = 0; d < 64; ++d) m += pr[d] * wv[d];
        sS[k3 * 64 + lane] = m;   // all sS readers finished before last barrier
    }
    __syncthreads();

    // Pt[b,o,c] += sum_k M[k,c] * Wp[(k*8+h), o]
    for (int q = tid; q < 1536; q += 192) {
        int o = q >> 6, c = q & 63;
        float v = 0.f;
        #pragma unroll
        for (int k = 0; k < 3; ++k)
            v += sS[k * 64 + c] * Wp[(k * 8 + h) * 24 + o];
        atomicAdd(&Pt[b * 1536 + o * 64 + c], v);
    }
}

// ---------------------------------------------------------------------------
// K3: fully fused positional branch + projection (UNCHANGED from baseline):
//   phase 1: kproj imap@Wk on 12x12 halo -> kbuf (zero outside image = SAME pad)
//   phase 2: y1 = gelu(conv1) on 10x10 -> y1l (ring outside image forced to 0)
//   phase 3: out = fea@P + bp + conv2(y1l) on 8x8
// ---------------------------------------------------------------------------
__global__ __launch_bounds__(192, 2) void conv_fused(
    const float* __restrict__ imap, const float* __restrict__ Wk,
    const float* __restrict__ c1w,  const float* __restrict__ fea,
    const float* __restrict__ c2w,  const float* __restrict__ Pt,
    const float* __restrict__ bp,   float* __restrict__ outp)
{
    __shared__ __align__(16) float kbuf[144 * 28];  // 12x12 halo, stride 28
    __shared__ __align__(16) float y1l[100 * 28];   // 10x10, stride 28

    const int tid = threadIdx.x;
    const int blk = blockIdx.x;
    const int b = blk >> 8, ti = (blk >> 4) & 15, tj = blk & 15;
    const int i0 = ti * 8, j0 = tj * 8;
    const int o = tid % 24, jj = tid / 24;   // o: out-channel; jj: 0..7
    const int g = o >> 3;

    // ---- phase 1: kproj on the 12x12 halo (threads 0..143) ----
    if (tid < 144) {
        const int pi = tid / 12, pj = tid % 12;
        const int gi = i0 + pi - 2, gj = j0 + pj - 2;
        float kv[24];
        #pragma unroll
        for (int j = 0; j < 24; ++j) kv[j] = 0.f;
        if (gi >= 0 && gi < HH && gj >= 0 && gj < WW) {
            const float4* m4 = (const float4*)(imap + (((long)b * HH + gi) * WW + gj) * 24);
            float m[24];
            #pragma unroll
            for (int i = 0; i < 6; ++i) {
                float4 v = m4[i];
                m[4*i+0]=v.x; m[4*i+1]=v.y; m[4*i+2]=v.z; m[4*i+3]=v.w;
            }
            for (int i = 0; i < 24; ++i) {
                float mi = m[i];
                #pragma unroll
                for (int j = 0; j < 24; ++j) kv[j] += mi * Wk[i * 24 + j];
            }
        }
        #pragma unroll
        for (int j = 0; j < 24; ++j) kbuf[tid * 28 + j] = kv[j];
    }
    __syncthreads();

    // ---- phase 2: y1 = gelu(conv1) on 10x10 -> y1l ----
    {
        float wr[8][9];   // wr[ic][di*3+dj], OIHW-linear
        {
            const float4* wp = (const float4*)(c1w + o * 72);
            #pragma unroll
            for (int t = 0; t < 18; ++t) ((float4*)wr)[t] = wp[t];
        }
        for (int task = tid; task < 240; task += 192) {
            const int r = task / 24;           // y1l row 0..9
            float wc[3][3][8];                 // [col slot][di][ic]
            #pragma unroll
            for (int slot = 0; slot < 2; ++slot)
                #pragma unroll
                for (int di = 0; di < 3; ++di) {
                    const float* p = kbuf + ((r + di) * 12 + slot) * 28 + g * 8;
                    *(float4*)&wc[slot][di][0] = *(const float4*)(p);
                    *(float4*)&wc[slot][di][4] = *(const float4*)(p + 4);
                }
            #pragma unroll
            for (int c = 0; c < 10; ++c) {
                const int s2 = (c + 2) % 3;
                #pragma unroll
                for (int di = 0; di < 3; ++di) {
                    const float* p = kbuf + ((r + di) * 12 + (c + 2)) * 28 + g * 8;
                    *(float4*)&wc[s2][di][0] = *(const float4*)(p);
                    *(float4*)&wc[s2][di][4] = *(const float4*)(p + 4);
                }
                float s = 0.f;
                #pragma unroll
                for (int dj = 0; dj < 3; ++dj) {
                    const int sl = (c + dj) % 3;
                    #pragma unroll
                    for (int di = 0; di < 3; ++di)
                        #pragma unroll
                        for (int ic = 0; ic < 8; ++ic)
                            s += wc[sl][di][ic] * wr[ic][di * 3 + dj];
                }
                const int gi = i0 + r - 1, gj = j0 + c - 1;
                float val = 0.f;
                if (gi >= 0 && gi < HH && gj >= 0 && gj < WW)
                    val = 0.5f * s * (1.f + erff(s * 0.70710678f));
                y1l[(r * 10 + c) * 28 + o] = val;
            }
        }
    }
    __syncthreads();

    // ---- phase 3: out = fea@P + bp + conv2(y1l) on 8x8 ----
    float wr[8][9];
    {
        const float4* wp = (const float4*)(c2w + o * 72);
        #pragma unroll
        for (int t = 0; t < 18; ++t) ((float4*)wr)[t] = wp[t];
    }

    float acc[8];
    {
        const float bo = bp[o];
        #pragma unroll
        for (int ii = 0; ii < 8; ++ii) acc[ii] = bo;
        const float* PtRow = Pt + b * 1536 + o * 64;
        const float* feaB = fea + (((long)(b * HH + i0)) * WW + (j0 + jj)) * 64;
        for (int cq = 0; cq < 16; ++cq) {
            float4 p = *(const float4*)(PtRow + cq * 4);
            #pragma unroll
            for (int ii = 0; ii < 8; ++ii) {
                float4 f = *(const float4*)(feaB + (long)ii * WW * 64 + cq * 4);
                acc[ii] += f.x * p.x + f.y * p.y + f.z * p.z + f.w * p.w;
            }
        }
    }

    float win[3][3][8];   // [row slot][dj][ic]
    #define LROW(R, SLOT)                                                     \
    {                                                                         \
        const float* rp_ = y1l + ((R) * 10 + jj) * 28 + g * 8;                \
        *(float4*)&win[SLOT][0][0] = *(const float4*)(rp_);                   \
        *(float4*)&win[SLOT][0][4] = *(const float4*)(rp_ + 4);               \
        *(float4*)&win[SLOT][1][0] = *(const float4*)(rp_ + 28);              \
        *(float4*)&win[SLOT][1][4] = *(const float4*)(rp_ + 32);              \
        *(float4*)&win[SLOT][2][0] = *(const float4*)(rp_ + 56);              \
        *(float4*)&win[SLOT][2][4] = *(const float4*)(rp_ + 60);              \
    }

    LROW(0, 0)
    LROW(1, 1)
    #pragma unroll
    for (int ii = 0; ii < 8; ++ii) {
        LROW(ii + 2, (ii + 2) % 3)
        float s = 0.f;
        #pragma unroll
        for (int di = 0; di < 3; ++di) {
            const int slot = (ii + di) % 3;
            #pragma unroll
            for (int dj = 0; dj < 3; ++dj)
                #pragma unroll
                for (int ic = 0; ic < 8; ++ic)
                    s += win[slot][dj][ic] * wr[ic][di * 3 + dj];
        }
        outp[((long)((b * HH + i0 + ii) * WW + j0)) * 24 + tid] = acc[ii] + s;
    }
    #undef LROW
}

// ---------------------------------------------------------------------------
extern "C" void kernel_launch(void* const* d_in, const int* in_sizes, int n_in,
                              void* d_out, int out_size, void* d_ws, size_t ws_size,
                              hipStream_t stream) {
    const float* x_in    = (const float*)d_in[0];
    const float* fea     = (const float*)d_in[1];
    const float* imap    = (const float*)d_in[2];
    const float* Wq      = (const float*)d_in[3];
    const float* Wk      = (const float*)d_in[4];
    const float* Wv      = (const float*)d_in[5];
    const float* rescale = (const float*)d_in[6];
    const float* Wp      = (const float*)d_in[7];
    const float* bp      = (const float*)d_in[8];
    const float* c1w     = (const float*)d_in[9];
    const float* c2w     = (const float*)d_in[10];
    float* out = (float*)d_out;

    float* ws = (float*)d_ws;
    float* Sp = ws;            // 4*1536 floats
    float* Pt = ws + 6144;     // 4*1536 floats

    hipMemsetAsync(ws, 0, 12288 * sizeof(float), stream);
    s_reduce<<<1024, 256, 0, stream>>>(imap, x_in, Sp);
    attn_fused<<<32, 192, 0, stream>>>(Sp, Wk, Wq, Wv, rescale, Wp, Pt);
    conv_fused<<<BB * 256, 192, 0, stream>>>(imap, Wk, c1w, fea, c2w, Pt, bp, out);
}